// Round 6
// baseline (296.651 us; speedup 1.0000x reference)
//
#include <hip/hip_runtime.h>
#include <math.h>

#define NEG_INF -1000000000.0f

// Problem constants
#define WL_  20
#define D1_  300
#define D2_  300
#define OUT_ 300
#define BS_  4096                 // (b,s) pairs
#define PPB  2                    // pairs per tile
#define TPB  4                    // tiles per block (persistent pipeline)
#define NBLKP (BS_ / (PPB * TPB)) // 512 blocks
#define BM   40                   // rows per tile (2 pairs x 20 words)
#define MT   3                    // M-tiles of 16 (rows 40..47 are zero pad)
#define KS   10                   // k-steps of 32 (K = 320)
#define FR   512                  // shorts per fragment slab [64 lanes][8]
#define SLABS (MT * KS)           // 30 A-slabs per tile

typedef __attribute__((ext_vector_type(8))) short bf16x8;
typedef __attribute__((ext_vector_type(8))) short short8v;
typedef __attribute__((ext_vector_type(4))) float f32x4;
typedef __attribute__((ext_vector_type(4))) unsigned int uint4v;

// Fallback storage (only used if workspace too small). Preferred path: d_ws.
__device__ short g_Bpk[KS * 20 * FR];
__device__ float g_vlin[(size_t)BS_ * 320];

__device__ inline short f2bf(float f) {
    unsigned u = __float_as_uint(f);
    u += 0x7FFFu + ((u >> 16) & 1u);   // RNE
    return (short)(u >> 16);
}
__device__ inline float bf2f(short s) {
    return __uint_as_float(((unsigned)(unsigned short)s) << 16);
}

// round-half-up fp32->bf16 pack of 8 floats -> 16B fragment store
__device__ inline void pack_store(short* dst, int s, int lane, float4 fa, float4 fb) {
    unsigned u0 = __float_as_uint(fa.x) + 0x8000u;
    unsigned u1 = __float_as_uint(fa.y) + 0x8000u;
    unsigned u2 = __float_as_uint(fa.z) + 0x8000u;
    unsigned u3 = __float_as_uint(fa.w) + 0x8000u;
    unsigned u4 = __float_as_uint(fb.x) + 0x8000u;
    unsigned u5 = __float_as_uint(fb.y) + 0x8000u;
    unsigned u6 = __float_as_uint(fb.z) + 0x8000u;
    unsigned u7 = __float_as_uint(fb.w) + 0x8000u;
    uint4v w;
    w.x = __builtin_amdgcn_perm(u1, u0, 0x07060302u);
    w.y = __builtin_amdgcn_perm(u3, u2, 0x07060302u);
    w.z = __builtin_amdgcn_perm(u5, u4, 0x07060302u);
    w.w = __builtin_amdgcn_perm(u7, u6, 0x07060302u);
    *(uint4v*)(dst + ((size_t)s * 64 + lane) * 8) = w;
}

#define GB (KS * 20 * 64)         // 12,800 Ws fragment-groups
#define PREP_BLKS ((GB + 255) / 256)   // 50
#define VLIN_BLKS 256

// ONE kernel: blocks [0,50) pack Ws -> Bpk; blocks [50,306) compute
// vlin[row][col] = vec . Wv + bias (4096 x 320), packing Wv fragments
// directly from fp32 W (no Wvpk intermediate, no inter-kernel dependency).
__global__ __launch_bounds__(256) void prep_and_vlin(
    const float* __restrict__ W, const float* __restrict__ bias,
    const float* __restrict__ vec,
    short* Bpk, float* vlin)
{
    if (!Bpk) { Bpk = g_Bpk; vlin = g_vlin; }
    const int tid  = threadIdx.x;
    const int lane = tid & 63;
    const int q = lane >> 4, l15 = lane & 15;

    if (blockIdx.x < PREP_BLKS) {
        const int id = blockIdx.x * 256 + tid;
        if (id >= GB) return;
        const int g = id >> 6;
        const int ks = g / 20, tile = g % 20;
        const int o = tile * 16 + l15, k0 = ks * 32 + q * 8;
        short8v o8 = {0, 0, 0, 0, 0, 0, 0, 0};
        if (o < OUT_) {
            #pragma unroll
            for (int e = 0; e < 8; ++e) {
                const int k = k0 + e;
                if (k < D1_) o8[e] = f2bf(W[(size_t)o * (D1_ + D2_) + k]);
            }
        }
        *(short8v*)(Bpk + (size_t)id * 8) = o8;
        return;
    }

    // ---- vlin part ----
    const int mtile = blockIdx.x - PREP_BLKS;   // 0..255
    const int wv = tid >> 6;                    // j-tile group 0..3

    // A-fragments for rows mtile*16+l15: issue all loads, then convert.
    const float* vp = vec + (size_t)(mtile * 16 + l15) * D2_;
    float4 ra[KS], rb[KS];
    #pragma unroll
    for (int ks = 0; ks < KS; ++ks) {
        const int k0 = ks * 32 + q * 8;
        float4 fa = {0.f, 0.f, 0.f, 0.f}, fb = {0.f, 0.f, 0.f, 0.f};
        if (k0 < 296) { fa = *(const float4*)(vp + k0); fb = *(const float4*)(vp + k0 + 4); }
        else if (k0 == 296) { fa = *(const float4*)(vp + k0); }
        ra[ks] = fa; rb[ks] = fb;
    }
    bf16x8 frag[KS];
    #pragma unroll
    for (int ks = 0; ks < KS; ++ks) {
        const int k0 = ks * 32 + q * 8;
        const float f[8] = {ra[ks].x, ra[ks].y, ra[ks].z, ra[ks].w,
                            rb[ks].x, rb[ks].y, rb[ks].z, rb[ks].w};
        short8v av = {0, 0, 0, 0, 0, 0, 0, 0};
        #pragma unroll
        for (int e = 0; e < 8; ++e) {
            const int k = k0 + e;
            if (k < D2_)       av[e] = f2bf(f[e]);
            else if (k == 319) av[e] = (short)0x3F80;   // 1.0 (bias column)
        }
        frag[ks] = (bf16x8)av;
    }

    f32x4 acc[5];
    #pragma unroll
    for (int j = 0; j < 5; ++j) acc[j] = {0.f, 0.f, 0.f, 0.f};

    // B built inline from W (Wv half) + bias. Same f2bf rounding and same
    // ascending-ks accumulation order as the old Wvpk path -> bit-identical.
    #pragma unroll
    for (int j = 0; j < 5; ++j) {
        const int jt = wv * 5 + j;
        const int o = jt * 16 + l15;
        float4 ba[KS], bb[KS];
        float bv = 0.f;
        if (o < OUT_) {
            const float* wp = W + (size_t)o * (D1_ + D2_) + D1_;
            #pragma unroll
            for (int ks = 0; ks < KS; ++ks) {
                const int k0 = ks * 32 + q * 8;
                float4 fa = {0.f, 0.f, 0.f, 0.f}, fb = {0.f, 0.f, 0.f, 0.f};
                if (k0 < 296) { fa = *(const float4*)(wp + k0); fb = *(const float4*)(wp + k0 + 4); }
                else if (k0 == 296) { fa = *(const float4*)(wp + k0); }
                ba[ks] = fa; bb[ks] = fb;
            }
            bv = bias[o];
        } else {
            #pragma unroll
            for (int ks = 0; ks < KS; ++ks) {
                ba[ks] = {0.f, 0.f, 0.f, 0.f}; bb[ks] = {0.f, 0.f, 0.f, 0.f};
            }
        }
        #pragma unroll
        for (int ks = 0; ks < KS; ++ks) {
            const int k0 = ks * 32 + q * 8;
            const float f[8] = {ba[ks].x, ba[ks].y, ba[ks].z, ba[ks].w,
                                bb[ks].x, bb[ks].y, bb[ks].z, bb[ks].w};
            short8v bvv = {0, 0, 0, 0, 0, 0, 0, 0};
            #pragma unroll
            for (int e = 0; e < 8; ++e) {
                const int k = k0 + e;
                if (k < D2_)       bvv[e] = f2bf(f[e]);
                else if (k == 319) bvv[e] = f2bf(bv);
            }
            acc[j] = __builtin_amdgcn_mfma_f32_16x16x32_bf16(frag[ks], (bf16x8)bvv, acc[j], 0, 0, 0);
        }
    }

    const int row0 = mtile * 16 + q * 4;
    #pragma unroll
    for (int j = 0; j < 5; ++j)
        #pragma unroll
        for (int r = 0; r < 4; ++r)
            vlin[(size_t)(row0 + r) * 320 + (wv * 5 + j) * 16 + l15] = acc[j][r];
}

// Persistent pipelined attention: 512 blocks x 4 tiles. Double-buffered Am;
// tile t+1's global loads are issued one full iteration early (T14 pattern:
// issue-early / write-late), its LDS pack lands after the alpha barrier of
// tile t -> HBM latency and pack VALU hide under GEMM/epilogue compute.
// All __syncthreads() are in uniform control flow; global indices bounded
// (gt0+t+2 <= 2047 guarded by t+2<TPB); LDS 62,240 B static.
__global__ __launch_bounds__(256, 2) void attn_fused(
    const float* __restrict__ seq,   // fp32 [4096,20,300]
    const int*   __restrict__ masks,
    const float* __restrict__ vvec,
    const short* Bpk,
    const float* vlinbuf,
    float*       __restrict__ out)
{
    if (!Bpk) { Bpk = g_Bpk; vlinbuf = g_vlin; }

    __shared__ short Am[2][SLABS * FR];   // 2 x 30,720 B
    __shared__ float sp[4][BM];           // 640 B
    __shared__ float alpha_lds[BM];       // 160 B  — total 62,240 B

    const int tid  = threadIdx.x;
    const int lane = tid & 63;
    const int wv   = tid >> 6;            // 0..3
    const int q    = lane >> 4;
    const int l15  = lane & 15;
    const int blk  = blockIdx.x;
    const int gt0  = blk * TPB;

    // pipeline registers
    float4 ra[8], rb[8];                  // seq prefetch (held 1 iteration)
    float vlpc[PPB][5], vlpn[PPB][5];     // vlin cur / next
    int mkc = 0, mkn = 0;                 // mask cur / next (tid<64)

    // issue all global loads for tile gt (seq -> ra/rb, vlin -> vlpn, mask -> mkn)
    auto issue_tile = [&](int gt) {
        const float* sbase = seq + (size_t)gt * BM * D1_;
        #pragma unroll
        for (int it = 0; it < 8; ++it) {
            const int s = wv + it * 4;
            float4 fa = {0.f, 0.f, 0.f, 0.f}, fb = {0.f, 0.f, 0.f, 0.f};
            if (s < SLABS) {
                const int tile = s / KS, ks = s % KS;
                const int row = tile * 16 + l15;
                const int k0 = ks * 32 + q * 8;
                if (row < BM) {
                    const float* p = sbase + (size_t)row * D1_ + k0;
                    if (k0 < 296) { fa = *(const float4*)p; fb = *(const float4*)(p + 4); }
                    else if (k0 == 296) { fa = *(const float4*)p; }
                }
            }
            ra[it] = fa; rb[it] = fb;
        }
        #pragma unroll
        for (int p = 0; p < PPB; ++p)
            #pragma unroll
            for (int j = 0; j < 5; ++j)
                vlpn[p][j] = vlinbuf[(size_t)(gt * PPB + p) * 320 + wv * 80 + j * 16 + l15];
        if (tid < PPB * 32) {
            const int p = tid >> 5, w = tid & 31;
            mkn = (w < WL_) ? masks[(size_t)(gt * PPB + p) * WL_ + w] : 0;
        }
    };
    // convert + store the prefetched tile into an Am buffer
    auto pack_tile = [&](short* dst) {
        #pragma unroll
        for (int it = 0; it < 8; ++it) {
            const int s = wv + it * 4;
            if (s < SLABS) pack_store(dst, s, lane, ra[it], rb[it]);
        }
    };

    // v-vector (once)
    float vj[5];
    #pragma unroll
    for (int j = 0; j < 5; ++j) {
        const int col = wv * 80 + j * 16 + l15;
        vj[j] = (col < OUT_) ? vvec[col] : 0.f;
    }

    // ---- prologue: tile 0 load+pack, tile 1 loads in flight ----
    issue_tile(gt0);
    pack_tile(&Am[0][0]);
    #pragma unroll
    for (int p = 0; p < PPB; ++p)
        #pragma unroll
        for (int j = 0; j < 5; ++j) vlpc[p][j] = vlpn[p][j];
    mkc = mkn;
    issue_tile(gt0 + 1);

    short* cur = &Am[0][0];
    short* nxt = &Am[1][0];

    const short* pb[5];
    #pragma unroll
    for (int j = 0; j < 5; ++j)
        pb[j] = Bpk + (size_t)(wv * 5 + j) * FR + lane * 8;

    #pragma unroll 1
    for (int t = 0; t < TPB; ++t) {
        const int gt = gt0 + t;
        __syncthreads();                  // cur buffer fully packed

        // ---- GEMM: A from cur (LDS), B from L2 (frag-packed Bpk) ----
        f32x4 acc[MT][5];
        #pragma unroll
        for (int i = 0; i < MT; ++i)
            #pragma unroll
            for (int j = 0; j < 5; ++j) acc[i][j] = {0.f, 0.f, 0.f, 0.f};

        #pragma unroll
        for (int ks = 0; ks < KS; ++ks) {
            bf16x8 a[MT], b[5];
            #pragma unroll
            for (int i = 0; i < MT; ++i)
                a[i] = *(const bf16x8*)(cur + (((size_t)i * KS + ks) * 64 + lane) * 8);
            #pragma unroll
            for (int j = 0; j < 5; ++j)
                b[j] = *(const bf16x8*)(pb[j] + (size_t)ks * 20 * FR);
            #pragma unroll
            for (int i = 0; i < MT; ++i)
                #pragma unroll
                for (int j = 0; j < 5; ++j)
                    acc[i][j] = __builtin_amdgcn_mfma_f32_16x16x32_bf16(a[i], b[j], acc[i][j], 0, 0, 0);
        }

        // ---- epilogue: lin = acc + vlin; score = sum_o tanh(lin)*v[o] ----
        #pragma unroll
        for (int i = 0; i < MT; ++i) {
            #pragma unroll
            for (int r = 0; r < 4; ++r) {
                const int row = i * 16 + q * 4 + r;
                const bool hi = (row >= 20);
                float s = 0.f;
                #pragma unroll
                for (int j = 0; j < 5; ++j) {
                    const float vlv = (i == 0) ? vlpc[0][j]
                                    : (i == 2) ? vlpc[1][j]
                                    : (hi ? vlpc[1][j] : vlpc[0][j]);
                    const float x = acc[i][j][r] + vlv;
                    const float e = __expf(2.f * x);   // tanh = 1 - 2/(e^{2x}+1)
                    s += (1.f - 2.f / (e + 1.f)) * vj[j];
                }
                s += __shfl_xor(s, 1, 64);
                s += __shfl_xor(s, 2, 64);
                s += __shfl_xor(s, 4, 64);
                s += __shfl_xor(s, 8, 64);             // sum 16 cols of tile
                if (l15 == 0 && row < BM) sp[wv][row] = s;
            }
        }
        __syncthreads();

        // ---- wave-parallel masked softmax: 32 lanes per pair ----
        if (tid < PPB * 32) {
            const int p = tid >> 5;
            const int w = tid & 31;
            float s;
            if (w < WL_) {
                const int row = p * WL_ + w;
                const float sc = sp[0][row] + sp[1][row] + sp[2][row] + sp[3][row];
                s = (mkc == 0) ? NEG_INF : sc;
            } else {
                s = -INFINITY;
            }
            float m = s;
            #pragma unroll
            for (int off = 16; off; off >>= 1)
                m = fmaxf(m, __shfl_xor(m, off, 32));
            const float e = __expf(s - m);
            float sum = e;
            #pragma unroll
            for (int off = 16; off; off >>= 1)
                sum += __shfl_xor(sum, off, 32);
            if (w < WL_) alpha_lds[p * WL_ + w] = e / sum;
        }
        __syncthreads();

        // ---- weighted sum from cur (staggered w start vs bank quads) ----
        if (tid < PPB * 38) {
            const int p = tid / 38, ch = tid % 38;
            const int ks2 = ch >> 2, q2 = ch & 3;
            const int wst = ch % WL_;
            float o8[8] = {0.f, 0.f, 0.f, 0.f, 0.f, 0.f, 0.f, 0.f};
            #pragma unroll
            for (int wi = 0; wi < WL_; ++wi) {
                int w = wst + wi; if (w >= WL_) w -= WL_;
                const int row = p * WL_ + w;
                const int tl = row >> 4, l = row & 15;
                const bf16x8 s8 = *(const bf16x8*)(cur + (((size_t)tl * KS + ks2) * 64 + q2 * 16 + l) * 8);
                const float a = alpha_lds[row];
                #pragma unroll
                for (int e2 = 0; e2 < 8; ++e2) o8[e2] += a * bf2f(s8[e2]);
            }
            const int d0 = ch * 8, gp = gt * PPB + p;
            float* dst = out + (size_t)gp * OUT_ + d0;
            if (d0 + 8 <= OUT_) {
                *(float4*)dst       = {o8[0], o8[1], o8[2], o8[3]};
                *(float4*)(dst + 4) = {o8[4], o8[5], o8[6], o8[7]};
            } else {                                   // d0 == 296: last 4 only
                *(float4*)dst = {o8[0], o8[1], o8[2], o8[3]};
            }
        }

        // ---- pipeline advance: pack t+1 into spare buffer, issue t+2 ----
        if (t + 1 < TPB) {
            pack_tile(nxt);                // consumes ra/rb (issued iter t-1)
            #pragma unroll
            for (int p = 0; p < PPB; ++p)
                #pragma unroll
                for (int j = 0; j < 5; ++j) vlpc[p][j] = vlpn[p][j];
            mkc = mkn;
            if (t + 2 < TPB) issue_tile(gt0 + t + 2);
            short* tmp = cur; cur = nxt; nxt = tmp;
        }
    }
}

extern "C" void kernel_launch(void* const* d_in, const int* in_sizes, int n_in,
                              void* d_out, int out_size, void* d_ws, size_t ws_size,
                              hipStream_t stream) {
    const float* seq   = (const float*)d_in[0];
    const float* vec   = (const float*)d_in[1];
    const int*   masks = (const int*)d_in[2];
    const float* W     = (const float*)d_in[3];
    const float* b     = (const float*)d_in[4];
    const float* v     = (const float*)d_in[5];
    float* out = (float*)d_out;

    constexpr size_t SZ_B = sizeof(short) * (size_t)KS * 20 * FR;   // 204,800
    constexpr size_t SZ_L = sizeof(float) * (size_t)BS_ * 320;      // 5,242,880
    constexpr size_t NEED = SZ_B + SZ_L;                            // 5,447,680
    short *Bpk = nullptr;
    float *vlin = nullptr;
    if (d_ws && ws_size >= NEED) {
        char* p = (char*)d_ws;
        Bpk  = (short*)p; p += SZ_B;
        vlin = (float*)p;
    }

    prep_and_vlin<<<PREP_BLKS + VLIN_BLKS, 256, 0, stream>>>(W, b, vec, Bpk, vlin);
    attn_fused<<<NBLKP, 256, 0, stream>>>(seq, masks, v, Bpk, vlin, out);
}

// Round 8
// 202.292 us; speedup vs baseline: 1.4664x; 1.4664x over previous
//
#include <hip/hip_runtime.h>
#include <math.h>

#define NEG_INF -1000000000.0f

// Problem constants
#define WL_  20
#define D1_  300
#define D2_  300
#define OUT_ 300
#define BS_  4096                 // (b,s) pairs
#define PPB  2                    // pairs per block
#define NBLK (BS_ / PPB)          // 2048 blocks
#define BM   40                   // rows per block (2 pairs x 20 words)
#define MT   3                    // M-tiles of 16 (rows 40..47 are zero pad)
#define KS   10                   // k-steps of 32 (K = 320)
#define FR   512                  // shorts per fragment slab [64 lanes][8]
#define SLABS (MT * KS)           // 30 A-slabs per block

typedef __attribute__((ext_vector_type(8))) short bf16x8;
typedef __attribute__((ext_vector_type(4))) short bf16x4;
typedef __attribute__((ext_vector_type(8))) short short8v;
typedef __attribute__((ext_vector_type(4))) float f32x4;
typedef __attribute__((ext_vector_type(4))) unsigned int uint4v;

// Fallback storage (only used if workspace too small). Preferred path: d_ws.
__device__ short g_Bpk[KS * 20 * FR];
__device__ float g_vlin[(size_t)BS_ * 320];

__device__ inline short f2bf(float f) {
    unsigned u = __float_as_uint(f);
    u += 0x7FFFu + ((u >> 16) & 1u);   // RNE
    return (short)(u >> 16);
}
__device__ inline float bf2f(short s) {
    return __uint_as_float(((unsigned)(unsigned short)s) << 16);
}

// round-half-up fp32->bf16 pack of 8 floats -> 16B fragment store
__device__ inline void pack_store(short* dst, int s, int lane, float4 fa, float4 fb) {
    unsigned u0 = __float_as_uint(fa.x) + 0x8000u;
    unsigned u1 = __float_as_uint(fa.y) + 0x8000u;
    unsigned u2 = __float_as_uint(fa.z) + 0x8000u;
    unsigned u3 = __float_as_uint(fa.w) + 0x8000u;
    unsigned u4 = __float_as_uint(fb.x) + 0x8000u;
    unsigned u5 = __float_as_uint(fb.y) + 0x8000u;
    unsigned u6 = __float_as_uint(fb.z) + 0x8000u;
    unsigned u7 = __float_as_uint(fb.w) + 0x8000u;
    uint4v w;
    w.x = __builtin_amdgcn_perm(u1, u0, 0x07060302u);
    w.y = __builtin_amdgcn_perm(u3, u2, 0x07060302u);
    w.z = __builtin_amdgcn_perm(u5, u4, 0x07060302u);
    w.w = __builtin_amdgcn_perm(u7, u6, 0x07060302u);
    *(uint4v*)(dst + ((size_t)s * 64 + lane) * 8) = w;
}

#define GB (KS * 20 * 64)         // 12,800 Ws fragment-groups
#define PREP_BLKS ((GB + 255) / 256)   // 50
#define VLIN_BLKS 256

// ONE kernel: blocks [0,50) pack Ws -> Bpk; blocks [50,306) compute
// vlin[row][col] = vec . Wv + bias (4096 x 320), packing Wv fragments
// directly from fp32 W (no Wvpk intermediate, no inter-kernel dependency).
__global__ __launch_bounds__(256) void prep_and_vlin(
    const float* __restrict__ W, const float* __restrict__ bias,
    const float* __restrict__ vec,
    short* Bpk, float* vlin)
{
    if (!Bpk) { Bpk = g_Bpk; vlin = g_vlin; }
    const int tid  = threadIdx.x;
    const int lane = tid & 63;
    const int q = lane >> 4, l15 = lane & 15;

    if (blockIdx.x < PREP_BLKS) {
        const int id = blockIdx.x * 256 + tid;
        if (id >= GB) return;
        const int g = id >> 6;
        const int ks = g / 20, tile = g % 20;
        const int o = tile * 16 + l15, k0 = ks * 32 + q * 8;
        short8v o8 = {0, 0, 0, 0, 0, 0, 0, 0};
        if (o < OUT_) {
            #pragma unroll
            for (int e = 0; e < 8; ++e) {
                const int k = k0 + e;
                if (k < D1_) o8[e] = f2bf(W[(size_t)o * (D1_ + D2_) + k]);
            }
        }
        *(short8v*)(Bpk + (size_t)id * 8) = o8;
        return;
    }

    // ---- vlin part ----
    const int mtile = blockIdx.x - PREP_BLKS;   // 0..255
    const int wv = tid >> 6;                    // j-tile group 0..3

    // A-fragments for rows mtile*16+l15: issue all loads, then convert.
    const float* vp = vec + (size_t)(mtile * 16 + l15) * D2_;
    float4 ra[KS], rb[KS];
    #pragma unroll
    for (int ks = 0; ks < KS; ++ks) {
        const int k0 = ks * 32 + q * 8;
        float4 fa = {0.f, 0.f, 0.f, 0.f}, fb = {0.f, 0.f, 0.f, 0.f};
        if (k0 < 296) { fa = *(const float4*)(vp + k0); fb = *(const float4*)(vp + k0 + 4); }
        else if (k0 == 296) { fa = *(const float4*)(vp + k0); }
        ra[ks] = fa; rb[ks] = fb;
    }
    bf16x8 frag[KS];
    #pragma unroll
    for (int ks = 0; ks < KS; ++ks) {
        const int k0 = ks * 32 + q * 8;
        const float f[8] = {ra[ks].x, ra[ks].y, ra[ks].z, ra[ks].w,
                            rb[ks].x, rb[ks].y, rb[ks].z, rb[ks].w};
        short8v av = {0, 0, 0, 0, 0, 0, 0, 0};
        #pragma unroll
        for (int e = 0; e < 8; ++e) {
            const int k = k0 + e;
            if (k < D2_)       av[e] = f2bf(f[e]);
            else if (k == 319) av[e] = (short)0x3F80;   // 1.0 (bias column)
        }
        frag[ks] = (bf16x8)av;
    }

    f32x4 acc[5];
    #pragma unroll
    for (int j = 0; j < 5; ++j) acc[j] = {0.f, 0.f, 0.f, 0.f};

    // B built inline from W (Wv half) + bias. Same f2bf rounding and same
    // ascending-ks accumulation order as the original Wvpk path.
    #pragma unroll
    for (int j = 0; j < 5; ++j) {
        const int jt = wv * 5 + j;
        const int o = jt * 16 + l15;
        float4 ba[KS], bb[KS];
        float bv = 0.f;
        if (o < OUT_) {
            const float* wp = W + (size_t)o * (D1_ + D2_) + D1_;
            #pragma unroll
            for (int ks = 0; ks < KS; ++ks) {
                const int k0 = ks * 32 + q * 8;
                float4 fa = {0.f, 0.f, 0.f, 0.f}, fb = {0.f, 0.f, 0.f, 0.f};
                if (k0 < 296) { fa = *(const float4*)(wp + k0); fb = *(const float4*)(wp + k0 + 4); }
                else if (k0 == 296) { fa = *(const float4*)(wp + k0); }
                ba[ks] = fa; bb[ks] = fb;
            }
            bv = bias[o];
        } else {
            #pragma unroll
            for (int ks = 0; ks < KS; ++ks) {
                ba[ks] = {0.f, 0.f, 0.f, 0.f}; bb[ks] = {0.f, 0.f, 0.f, 0.f};
            }
        }
        #pragma unroll
        for (int ks = 0; ks < KS; ++ks) {
            const int k0 = ks * 32 + q * 8;
            const float f[8] = {ba[ks].x, ba[ks].y, ba[ks].z, ba[ks].w,
                                bb[ks].x, bb[ks].y, bb[ks].z, bb[ks].w};
            short8v bvv = {0, 0, 0, 0, 0, 0, 0, 0};
            #pragma unroll
            for (int e = 0; e < 8; ++e) {
                const int k = k0 + e;
                if (k < D2_)       bvv[e] = f2bf(f[e]);
                else if (k == 319) bvv[e] = f2bf(bv);
            }
            acc[j] = __builtin_amdgcn_mfma_f32_16x16x32_bf16(frag[ks], (bf16x8)bvv, acc[j], 0, 0, 0);
        }
    }

    const int row0 = mtile * 16 + q * 4;
    #pragma unroll
    for (int j = 0; j < 5; ++j)
        #pragma unroll
        for (int r = 0; r < 4; ++r)
            vlin[(size_t)(row0 + r) * 320 + (wv * 5 + j) * 16 + l15] = acc[j][r];
}

// r4 structure, 2 barriers. The weighted sum's alpha redistribution is done
// under a WAVE-UNIFORM branch (tid<192): waves 0-2 fully active, so the
// __shfl never sources an exec-masked-off lane (r7's failure mode: the
// compiler can sink alpha's final division into a divergent branch, leaving
// inactive lanes' alpha registers undefined for ds_bpermute).
__global__ __launch_bounds__(256, 2) void attn_fused(
    const float* __restrict__ seq,   // fp32 [4096,20,300]
    const int*   __restrict__ masks,
    const float* __restrict__ vvec,
    const short* Bpk,
    const float* vlinbuf,
    float*       __restrict__ out)
{
    if (!Bpk) { Bpk = g_Bpk; vlinbuf = g_vlin; }

    __shared__ short Am[SLABS * FR];      // 30,720 B — bf16 A fragments
    __shared__ float sp[4][BM];           // 640 B   — total 31,360 B

    const int tid  = threadIdx.x;
    const int lane = tid & 63;
    const int wv   = tid >> 6;            // 0..3
    const int q    = lane >> 4;
    const int l15  = lane & 15;
    const int blk  = blockIdx.x;

    // ---- Phase 1: fp32 seq tile -> bf16 fragment slabs in LDS ----
    // 30 slabs / 4 waves = 8 rounds, fully unrolled load-all-then-pack.
    {
        const float* sbase = seq + (size_t)blk * BM * D1_;
        float4 ra[8], rb[8];
        #pragma unroll
        for (int it = 0; it < 8; ++it) {
            const int s = wv + it * 4;
            float4 fa = {0.f, 0.f, 0.f, 0.f}, fb = {0.f, 0.f, 0.f, 0.f};
            if (s < SLABS) {
                const int tile = s / KS, ks = s % KS;
                const int row = tile * 16 + l15;
                const int k0 = ks * 32 + q * 8;
                if (row < BM) {
                    const float* p = sbase + (size_t)row * D1_ + k0;
                    if (k0 < 296) { fa = *(const float4*)p; fb = *(const float4*)(p + 4); }
                    else if (k0 == 296) { fa = *(const float4*)p; }
                }
            }
            ra[it] = fa; rb[it] = fb;
        }
        #pragma unroll
        for (int it = 0; it < 8; ++it) {
            const int s = wv + it * 4;
            if (s < SLABS) pack_store(Am, s, lane, ra[it], rb[it]);
        }
    }

    // Preloads before the barrier (latency hidden under the staging drain):
    // v-vector, vlin row slices, and this lane's softmax mask word.
    float vj[5];
    #pragma unroll
    for (int j = 0; j < 5; ++j) {
        const int col = wv * 80 + j * 16 + l15;
        vj[j] = (col < OUT_) ? vvec[col] : 0.f;
    }
    float vlp[PPB][5];
    #pragma unroll
    for (int p = 0; p < PPB; ++p)
        #pragma unroll
        for (int j = 0; j < 5; ++j)
            vlp[p][j] = vlinbuf[(size_t)(blk * PPB + p) * 320 + wv * 80 + j * 16 + l15];
    const int smg = lane >> 5;            // softmax group: pair index 0/1
    const int smw = lane & 31;            // word slot 0..31 (valid < 20)
    int mk = 0;
    if (smw < WL_) mk = masks[(size_t)(blk * PPB + smg) * WL_ + smw];
    __syncthreads();                      // B1: Am packed

    // ---- Phase 2: barrier-free GEMM. A from LDS, B from L2 (frag-packed) ----
    f32x4 acc[MT][5];
    #pragma unroll
    for (int i = 0; i < MT; ++i)
        #pragma unroll
        for (int j = 0; j < 5; ++j) acc[i][j] = {0.f, 0.f, 0.f, 0.f};

    const short* pb[5];
    #pragma unroll
    for (int j = 0; j < 5; ++j)
        pb[j] = Bpk + (size_t)(wv * 5 + j) * FR + lane * 8;

    #pragma unroll
    for (int ks = 0; ks < KS; ++ks) {
        bf16x8 a[MT], b[5];
        #pragma unroll
        for (int i = 0; i < MT; ++i)
            a[i] = *(const bf16x8*)(Am + (((size_t)i * KS + ks) * 64 + lane) * 8);
        #pragma unroll
        for (int j = 0; j < 5; ++j)
            b[j] = *(const bf16x8*)(pb[j] + (size_t)ks * 20 * FR);
        #pragma unroll
        for (int i = 0; i < MT; ++i)
            #pragma unroll
            for (int j = 0; j < 5; ++j)
                acc[i][j] = __builtin_amdgcn_mfma_f32_16x16x32_bf16(a[i], b[j], acc[i][j], 0, 0, 0);
    }

    // ---- epilogue: lin = acc + vlin; score[r] = sum_o tanh(lin) * v[o] ----
    #pragma unroll
    for (int i = 0; i < MT; ++i) {
        #pragma unroll
        for (int r = 0; r < 4; ++r) {
            const int row = i * 16 + q * 4 + r;
            const bool hi = (row >= 20);
            float s = 0.f;
            #pragma unroll
            for (int j = 0; j < 5; ++j) {
                const float vlv = (i == 0) ? vlp[0][j]
                                : (i == 2) ? vlp[1][j]
                                : (hi ? vlp[1][j] : vlp[0][j]);
                const float x = acc[i][j][r] + vlv;
                const float e = __expf(2.f * x);       // tanh = 1 - 2/(e^{2x}+1)
                s += (1.f - 2.f / (e + 1.f)) * vj[j];
            }
            s += __shfl_xor(s, 1, 64);
            s += __shfl_xor(s, 2, 64);
            s += __shfl_xor(s, 4, 64);
            s += __shfl_xor(s, 8, 64);                 // sum 16 cols of tile
            if (l15 == 0 && row < BM) sp[wv][row] = s;
        }
    }
    __syncthreads();                      // B2: sp complete (last barrier)

    // ---- per-wave redundant masked softmax (alpha stays in registers) ----
    // Every wave computes both pairs' softmax identically; no alpha LDS, no
    // third barrier. Lanes p*32+w (w<20) of each wave hold alpha[p][w].
    float alpha;
    {
        float s;
        if (smw < WL_) {
            const int row = smg * WL_ + smw;
            const float sc = sp[0][row] + sp[1][row] + sp[2][row] + sp[3][row];
            s = (mk == 0) ? NEG_INF : sc;
        } else {
            s = -INFINITY;                 // padding lanes: exp(-inf)=0
        }
        float m = s;
        #pragma unroll
        for (int off = 16; off; off >>= 1)
            m = fmaxf(m, __shfl_xor(m, off, 32));
        const float e = __expf(s - m);
        float sum = e;
        #pragma unroll
        for (int off = 16; off; off >>= 1)
            sum += __shfl_xor(sum, off, 32);
        alpha = e / sum;                   // valid where smw<20; 0 elsewhere
    }
    // Pin alpha into a VGPR here, in uniform control flow, so its definition
    // cannot be sunk into the (divergent at block scope) branch below.
    asm volatile("" : "+v"(alpha));

    // ---- weighted sum: 150 worker threads, 4-float chunks, alpha via shfl.
    // Branch is WAVE-uniform (tid<192 = waves 0..2); threads 150..191 run
    // with a clamped chunk id and skip the store, so every shfl source lane
    // (p*32+w, w<20) is active in its wave.
    if (tid < 192) {
        const bool live = (tid < PPB * 75);
        const int t2 = live ? tid : (PPB * 75 - 1);
        const int p = t2 / 75, ch = t2 % 75;
        const int d0 = ch * 4;
        const int ks2 = d0 >> 5;           // k-step of column d0
        const int q2 = (d0 >> 3) & 3;      // quad within k-step
        const int off = d0 & 7;            // 0 or 4 within the 8-elem frag
        const int wst = ch % WL_;
        float o4[4] = {0.f, 0.f, 0.f, 0.f};
        #pragma unroll
        for (int wi = 0; wi < WL_; ++wi) {
            int w = wst + wi; if (w >= WL_) w -= WL_;
            const int row = p * WL_ + w;
            const int tl = row >> 4, l = row & 15;
            const float aw = __shfl(alpha, p * 32 + w, 64);
            const bf16x4 s4 = *(const bf16x4*)(Am + (((size_t)tl * KS + ks2) * 64 + q2 * 16 + l) * 8 + off);
            #pragma unroll
            for (int e2 = 0; e2 < 4; ++e2) o4[e2] += aw * bf2f(s4[e2]);
        }
        if (live) {
            const int gp = blk * PPB + p;
            float* dst = out + (size_t)gp * OUT_ + d0;
            *(float4*)dst = {o4[0], o4[1], o4[2], o4[3]};
        }
    }
}

extern "C" void kernel_launch(void* const* d_in, const int* in_sizes, int n_in,
                              void* d_out, int out_size, void* d_ws, size_t ws_size,
                              hipStream_t stream) {
    const float* seq   = (const float*)d_in[0];
    const float* vec   = (const float*)d_in[1];
    const int*   masks = (const int*)d_in[2];
    const float* W     = (const float*)d_in[3];
    const float* b     = (const float*)d_in[4];
    const float* v     = (const float*)d_in[5];
    float* out = (float*)d_out;

    constexpr size_t SZ_B = sizeof(short) * (size_t)KS * 20 * FR;   // 204,800
    constexpr size_t SZ_L = sizeof(float) * (size_t)BS_ * 320;      // 5,242,880
    constexpr size_t NEED = SZ_B + SZ_L;                            // 5,447,680
    short *Bpk = nullptr;
    float *vlin = nullptr;
    if (d_ws && ws_size >= NEED) {
        char* p = (char*)d_ws;
        Bpk  = (short*)p; p += SZ_B;
        vlin = (float*)p;
    }

    prep_and_vlin<<<PREP_BLKS + VLIN_BLKS, 256, 0, stream>>>(W, b, vec, Bpk, vlin);
    attn_fused<<<NBLK, 256, 0, stream>>>(seq, masks, v, Bpk, vlin, out);
}